// Round 1
// baseline (341.176 us; speedup 1.0000x reference)
//
#include <hip/hip_runtime.h>

// PartPP: per (frame, part, channel) segment mean+max pooling.
// x: (32, 256, 30, 16, 16) fp32 ; labels: (32, 30, 16, 16) int ; out: (32, 256, 30, 16) fp32
//
// Memory-bound (~268 MB traffic, floor ~43 us). Strategy:
//  - bucket the 256 spatial positions by part label ONCE per block (shared across channels)
//  - stage 64 channel rows (64x256 fp32) into LDS coalesced (float4)
//  - reduction = dense gather over bucket ranges; scalar accumulators (no spill, no atomics)

#define C_DIM 256
#define S_DIM 30
#define P_NUM 16
#define HW 256
#define CH_PER_BLK 64
#define TILE_STRIDE 260   // floats: 1040B rows -> 16B aligned; (4*ch+pos)%32 decorrelates banks

__global__ __launch_bounds__(256, 2)
void partpp_pool_kernel(const float* __restrict__ x,
                        const int* __restrict__ labels,
                        float* __restrict__ out) {
    __shared__ float tile[CH_PER_BLK * TILE_STRIDE];  // 66560 B
    __shared__ int pos_sorted[HW];                    // positions grouped by part
    __shared__ int counts[P_NUM];
    __shared__ int cursor[P_NUM];
    __shared__ int offs[P_NUM + 1];

    const int t  = threadIdx.x;
    const int b  = blockIdx.x;
    const int f  = b >> 2;          // frame id 0..959  (f = n*30 + s)
    const int q  = b & 3;           // channel quarter
    const int ch0 = q * CH_PER_BLK;
    const int n  = f / S_DIM;
    const int s  = f - n * S_DIM;

    // ---- metadata: bucket the 256 positions by part (one position per thread) ----
    if (t < P_NUM) { counts[t] = 0; cursor[t] = 0; }
    __syncthreads();
    const int lab = labels[f * HW + t];   // coalesced 1KB, L2-resident across the 4 quarters
    atomicAdd(&counts[lab], 1);
    __syncthreads();
    if (t == 0) {
        int acc = 0;
        #pragma unroll
        for (int p = 0; p < P_NUM; ++p) { offs[p] = acc; acc += counts[p]; }
        offs[P_NUM] = acc;  // == 256
    }
    __syncthreads();
    {
        const int r = atomicAdd(&cursor[lab], 1);
        pos_sorted[offs[lab] + r] = t;
    }
    __syncthreads();

    // ---- stage 64 channel rows into LDS, fully coalesced float4 ----
    // x flat index: ((n*C + c)*S + s)*HW + pos ; channel stride = S*HW = 7680 floats
    const size_t xbase = ((size_t)(n * C_DIM + ch0) * S_DIM + s) * HW;
    #pragma unroll
    for (int j = 0; j < 16; ++j) {
        const int flat = j * 256 + t;     // float4 index over 64 rows x 64 cols
        const int row  = flat >> 6;
        const int col  = flat & 63;
        const float4 v = *(const float4*)(x + xbase + (size_t)row * (S_DIM * HW) + col * 4);
        *(float4*)(&tile[row * TILE_STRIDE + col * 4]) = v;
    }
    __syncthreads();

    // ---- reduce: thread = (channel, part-group); gather over bucket ranges ----
    const int ch_l = t >> 2;   // 0..63
    const int sub  = t & 3;    // handles parts [4*sub, 4*sub+4)
    const float* rowp = &tile[ch_l * TILE_STRIDE];

    float res[4];
    #pragma unroll
    for (int pi = 0; pi < 4; ++pi) {
        const int p  = sub * 4 + pi;
        const int jb = offs[p];
        const int je = offs[p + 1];
        float sum = 0.0f;
        float mx  = -3.0e38f;
        for (int j = jb; j < je; ++j) {
            const float v = rowp[pos_sorted[j]];   // pos broadcast within sub-group
            sum += v;
            mx = fmaxf(mx, v);
        }
        const int cnt = je - jb;
        // torch scatter_reduce amax include_self(-100); empty part -> 0
        res[pi] = (cnt > 0) ? (sum / (float)cnt + fmaxf(mx, -100.0f)) : 0.0f;
    }

    // out[((n*C + c)*S + s)*P + p] ; 4 consecutive lanes -> 16 contiguous floats
    float* op = out + ((size_t)(n * C_DIM + ch0 + ch_l) * S_DIM + s) * P_NUM + sub * 4;
    *(float4*)op = make_float4(res[0], res[1], res[2], res[3]);
}

extern "C" void kernel_launch(void* const* d_in, const int* in_sizes, int n_in,
                              void* d_out, int out_size, void* d_ws, size_t ws_size,
                              hipStream_t stream) {
    const float* x      = (const float*)d_in[0];
    const int*   labels = (const int*)d_in[1];
    float*       out    = (float*)d_out;

    // 960 frames x 4 channel-quarters
    dim3 grid(960 * 4), block(256);
    hipLaunchKernelGGL(partpp_pool_kernel, grid, block, 0, stream, x, labels, out);
}

// Round 2
// 336.734 us; speedup vs baseline: 1.0132x; 1.0132x over previous
//
#include <hip/hip_runtime.h>

// PartPP: per (frame, part, channel) segment mean+max pooling.
// x: (32, 256, 30, 16, 16) fp32 ; labels: (32, 30, 16, 16) int ; out: (32, 256, 30, 16) fp32
//
// Memory-bound (~268 MB traffic, floor ~43 us).
// R2 strategy: bucket-sort the DATA (not indices) into LDS during staging, so the
// reduce phase reads each part's values contiguously -- one independent ds_read per
// element, no dependent pos_sorted indirection. 32-channel tiles -> 34.5 KB LDS ->
// 4 blocks/CU for latency hiding. Global x-loads hoisted above metadata phase.

#define C_DIM 256
#define S_DIM 30
#define P_NUM 16
#define HW 256
#define CH_PER_BLK 32
#define TS 260   // floats per LDS row: 16B-aligned rows, stride%32==4 decorrelates banks

__global__ __launch_bounds__(256, 4)
void partpp_pool_kernel(const float* __restrict__ x,
                        const int* __restrict__ labels,
                        float* __restrict__ out) {
    __shared__ float tile[CH_PER_BLK * TS];   // 33280 B
    __shared__ int rank[HW];                  // pos -> bucket-sorted slot
    __shared__ int counts[P_NUM], cursor[P_NUM], offs[P_NUM + 1];

    const int t   = threadIdx.x;
    const int b   = blockIdx.x;
    const int f   = b >> 3;                // frame id 0..959 (f = n*30 + s)
    const int q   = b & 7;                 // channel octant
    const int ch0 = q * CH_PER_BLK;
    const int n   = f / S_DIM;
    const int s   = f - n * S_DIM;

    // ---- issue all global loads up front (overlap HBM latency with metadata) ----
    const int lab = labels[f * HW + t];    // 1KB coalesced, L2-resident across octants

    const size_t xbase = ((size_t)(n * C_DIM + ch0) * S_DIM + s) * HW;
    const int col = t & 63;                // float4 column 0..63
    float4 v[8];
    #pragma unroll
    for (int j = 0; j < 8; ++j) {
        const int row = j * 4 + (t >> 6);  // per wave: one contiguous 1KB row segment
        v[j] = *(const float4*)(x + xbase + (size_t)row * (S_DIM * HW) + col * 4);
    }

    // ---- metadata: histogram + scan + rank (shared across all 256 channels) ----
    if (t < P_NUM) { counts[t] = 0; cursor[t] = 0; }
    __syncthreads();
    atomicAdd(&counts[lab], 1);
    __syncthreads();
    if (t == 0) {
        int acc = 0;
        #pragma unroll
        for (int p = 0; p < P_NUM; ++p) { offs[p] = acc; acc += counts[p]; }
        offs[P_NUM] = acc;                 // == 256
    }
    __syncthreads();
    rank[t] = offs[lab] + atomicAdd(&cursor[lab], 1);
    __syncthreads();

    // ---- stage: scatter x into bucket-sorted LDS layout ----
    const int4 rk = *(const int4*)&rank[col * 4];   // 16B-aligned LDS read
    #pragma unroll
    for (int j = 0; j < 8; ++j) {
        const int row = j * 4 + (t >> 6);
        float* rp = &tile[row * TS];
        rp[rk.x] = v[j].x;
        rp[rk.y] = v[j].y;
        rp[rk.z] = v[j].z;
        rp[rk.w] = v[j].w;
    }
    __syncthreads();

    // ---- reduce: thread = (channel, part-pair); contiguous LDS reads ----
    const int ch  = t >> 3;    // 0..31
    const int sub = t & 7;     // parts {2*sub, 2*sub+1}
    const float* rowp = &tile[ch * TS];

    float res[2];
    #pragma unroll
    for (int pi = 0; pi < 2; ++pi) {
        const int p  = sub * 2 + pi;
        const int jb = offs[p];
        const int je = offs[p + 1];
        float sum = 0.0f;
        float mx  = -3.0e38f;
        for (int j = jb; j < je; ++j) {
            const float vv = rowp[j];      // independent reads -> pipelined
            sum += vv;
            mx = fmaxf(mx, vv);
        }
        // torch scatter_reduce amax include_self(-100); empty part -> 0
        res[pi] = (je > jb) ? (sum / (float)(je - jb) + fmaxf(mx, -100.0f)) : 0.0f;
    }

    // out[((n*C + c)*S + s)*P + p]; 8 lanes -> 64B contiguous per channel
    float* op = out + ((size_t)(n * C_DIM + ch0 + ch) * S_DIM + s) * P_NUM + sub * 2;
    *(float2*)op = make_float2(res[0], res[1]);
}

extern "C" void kernel_launch(void* const* d_in, const int* in_sizes, int n_in,
                              void* d_out, int out_size, void* d_ws, size_t ws_size,
                              hipStream_t stream) {
    const float* x      = (const float*)d_in[0];
    const int*   labels = (const int*)d_in[1];
    float*       out    = (float*)d_out;

    // 960 frames x 8 channel-octants
    dim3 grid(960 * 8), block(256);
    hipLaunchKernelGGL(partpp_pool_kernel, grid, block, 0, stream, x, labels, out);
}